// Round 6
// baseline (98.709 us; speedup 1.0000x reference)
//
#include <hip/hip_runtime.h>

// IWD projection: out[b,n,c] = sum_k x[b, nn_idx[n,k], c] * w[n,k]
// w[n,k] = (1/(dist+eps)) / sum_k(1/(dist+eps))
// B=4, N_in=49152, C=64, N_out=196608, K=4. f32 in/out.
//
// R6: bytes are near-floor; attack VALU + latency in the hot kernel.
//  - Pre-pass (fused with bf16 convert) computes per-row records
//    [w0..w3 (f32), idx*32 (i32) x4] with fast v_rcp -> no division and no
//    idx arithmetic in the gather kernel.
//  - Gather kernel: 2 rows/thread -> 8 independent 8 B gathers in flight.
//  - Keep R5 structure: bf16 channel-split planes (B,2,N_in,32) = 3.15 MB
//    per (b,h) plane, one plane per XCD via bid&7; nt f32 stores.

#define IWD_EPS 1e-8f

typedef float f32x4 __attribute__((ext_vector_type(4)));
typedef int   i32x4 __attribute__((ext_vector_type(4)));
typedef unsigned int u32x4 __attribute__((ext_vector_type(4)));
typedef unsigned int u32x2 __attribute__((ext_vector_type(2)));

__device__ __forceinline__ float bf16lo_to_f32(unsigned int v) {
    return __builtin_bit_cast(float, v << 16);
}
__device__ __forceinline__ float bf16hi_to_f32(unsigned int v) {
    return __builtin_bit_cast(float, v & 0xFFFF0000u);
}
__device__ __forceinline__ unsigned int f32_to_bf16_rne(float f) {
    unsigned int u = __builtin_bit_cast(unsigned int, f);
    u += 0x7FFFu + ((u >> 16) & 1u);
    return u >> 16;
}

// ---- Pass 1 (fused): convert x -> bf16 split planes, + row records ----
__global__ __launch_bounds__(256) void iwd_pre_kernel(
    const float* __restrict__ x, const int* __restrict__ nn_idx,
    const float* __restrict__ nn_dist, unsigned short* __restrict__ xs,
    unsigned int* __restrict__ wrec, int nconvblocks, int nvec8)
{
    constexpr int N_in = 49152;
    const int bid = blockIdx.x;
    if (bid < nconvblocks) {
        const int i = bid * 256 + threadIdx.x;     // one per 8 floats
        if (i >= nvec8) return;
        const int c    = (i * 8) & 63;
        const int rowb = (i * 8) >> 6;
        const int h    = c >> 5;
        const int c32  = c & 31;
        const int b    = rowb / N_in;
        const int row  = rowb - b * N_in;

        const f32x4 a = *reinterpret_cast<const f32x4*>(x + (size_t)i * 8);
        const f32x4 d = *reinterpret_cast<const f32x4*>(x + (size_t)i * 8 + 4);
        u32x4 p;
        p.x = f32_to_bf16_rne(a.x) | (f32_to_bf16_rne(a.y) << 16);
        p.y = f32_to_bf16_rne(a.z) | (f32_to_bf16_rne(a.w) << 16);
        p.z = f32_to_bf16_rne(d.x) | (f32_to_bf16_rne(d.y) << 16);
        p.w = f32_to_bf16_rne(d.z) | (f32_to_bf16_rne(d.w) << 16);
        unsigned short* dst = xs + (((size_t)(b * 2 + h) * N_in + row) * 32 + c32);
        __builtin_nontemporal_store(p, reinterpret_cast<u32x4*>(dst));
    } else {
        const int n = (bid - nconvblocks) * 256 + threadIdx.x;  // 768*256 == N_out
        const f32x4 d4 = *reinterpret_cast<const f32x4*>(nn_dist + (size_t)n * 4);
        const i32x4 id = *reinterpret_cast<const i32x4*>(nn_idx + (size_t)n * 4);
        const float i0 = __builtin_amdgcn_rcpf(d4.x + IWD_EPS);
        const float i1 = __builtin_amdgcn_rcpf(d4.y + IWD_EPS);
        const float i2 = __builtin_amdgcn_rcpf(d4.z + IWD_EPS);
        const float i3 = __builtin_amdgcn_rcpf(d4.w + IWD_EPS);
        const float r  = __builtin_amdgcn_rcpf(i0 + i1 + i2 + i3);
        f32x4 w; w.x = i0 * r; w.y = i1 * r; w.z = i2 * r; w.w = i3 * r;
        i32x4 off; off.x = id.x * 32; off.y = id.y * 32; off.z = id.z * 32; off.w = id.w * 32;
        unsigned int* rp = wrec + (size_t)n * 8;
        __builtin_nontemporal_store(__builtin_bit_cast(u32x4, w),
                                    reinterpret_cast<u32x4*>(rp));
        __builtin_nontemporal_store(__builtin_bit_cast(u32x4, off),
                                    reinterpret_cast<u32x4*>(rp + 4));
    }
}

// ---- Pass 2: gather (2 rows/thread, 8 gathers in flight) ----
__global__ __launch_bounds__(256) void IWD_ProjLayer_65876208386401_kernel(
    const unsigned short* __restrict__ xs,   // (B, 2, N_in, 32) bf16
    const unsigned int* __restrict__ wrec,   // (N_out, 8): w[4] f32, off[4] i32
    float* __restrict__ out)                 // (B, N_out, 64)
{
    constexpr int N_in  = 49152;
    constexpr int N_out = 196608;

    const int bid   = blockIdx.x;
    const int xcd   = bid & 7;          // dispatch round-robin residue
    const int b     = xcd >> 1;
    const int h     = xcd & 1;
    const int chunk = bid >> 3;         // [0, 3072)

    const int g   = threadIdx.x >> 3;          // row-group [0,32)
    const int c32 = (threadIdx.x & 7) * 4;     // channel quad in half
    const int n0  = chunk * 64 + g * 2;        // even row; also do n0+1

    const unsigned int* rp = wrec + (size_t)n0 * 8;
    const f32x4 wA = *reinterpret_cast<const f32x4*>(rp);
    const i32x4 oA = *reinterpret_cast<const i32x4*>(rp + 4);
    const f32x4 wB = *reinterpret_cast<const f32x4*>(rp + 8);
    const i32x4 oB = *reinterpret_cast<const i32x4*>(rp + 12);

    const unsigned short* plane = xs + (size_t)(b * 2 + h) * N_in * 32 + c32;

    // 8 independent gathers
    const u32x2 a0 = *reinterpret_cast<const u32x2*>(plane + oA.x);
    const u32x2 a1 = *reinterpret_cast<const u32x2*>(plane + oA.y);
    const u32x2 a2 = *reinterpret_cast<const u32x2*>(plane + oA.z);
    const u32x2 a3 = *reinterpret_cast<const u32x2*>(plane + oA.w);
    const u32x2 b0 = *reinterpret_cast<const u32x2*>(plane + oB.x);
    const u32x2 b1 = *reinterpret_cast<const u32x2*>(plane + oB.y);
    const u32x2 b2 = *reinterpret_cast<const u32x2*>(plane + oB.z);
    const u32x2 b3 = *reinterpret_cast<const u32x2*>(plane + oB.w);

    f32x4 oa, ob;
    oa.x = bf16lo_to_f32(a0.x) * wA.x + bf16lo_to_f32(a1.x) * wA.y
         + bf16lo_to_f32(a2.x) * wA.z + bf16lo_to_f32(a3.x) * wA.w;
    oa.y = bf16hi_to_f32(a0.x) * wA.x + bf16hi_to_f32(a1.x) * wA.y
         + bf16hi_to_f32(a2.x) * wA.z + bf16hi_to_f32(a3.x) * wA.w;
    oa.z = bf16lo_to_f32(a0.y) * wA.x + bf16lo_to_f32(a1.y) * wA.y
         + bf16lo_to_f32(a2.y) * wA.z + bf16lo_to_f32(a3.y) * wA.w;
    oa.w = bf16hi_to_f32(a0.y) * wA.x + bf16hi_to_f32(a1.y) * wA.y
         + bf16hi_to_f32(a2.y) * wA.z + bf16hi_to_f32(a3.y) * wA.w;

    ob.x = bf16lo_to_f32(b0.x) * wB.x + bf16lo_to_f32(b1.x) * wB.y
         + bf16lo_to_f32(b2.x) * wB.z + bf16lo_to_f32(b3.x) * wB.w;
    ob.y = bf16hi_to_f32(b0.x) * wB.x + bf16hi_to_f32(b1.x) * wB.y
         + bf16hi_to_f32(b2.x) * wB.z + bf16hi_to_f32(b3.x) * wB.w;
    ob.z = bf16lo_to_f32(b0.y) * wB.x + bf16lo_to_f32(b1.y) * wB.y
         + bf16lo_to_f32(b2.y) * wB.z + bf16lo_to_f32(b3.y) * wB.w;
    ob.w = bf16hi_to_f32(b0.y) * wB.x + bf16hi_to_f32(b1.y) * wB.y
         + bf16hi_to_f32(b2.y) * wB.z + bf16hi_to_f32(b3.y) * wB.w;

    float* opA = out + ((size_t)b * N_out + n0) * 64 + h * 32 + c32;
    __builtin_nontemporal_store(oa, reinterpret_cast<f32x4*>(opA));
    __builtin_nontemporal_store(ob, reinterpret_cast<f32x4*>(opA + 64));
}

// ---- Fallback (ws too small): direct-f32 kernel (R3) ----
__global__ __launch_bounds__(256) void iwd_f32_fallback_kernel(
    const float* __restrict__ x, const int* __restrict__ nn_idx,
    const float* __restrict__ nn_dist, float* __restrict__ out)
{
    constexpr int N_in = 49152, C = 64, N_out = 196608;
    const int bid = blockIdx.x, xcd = bid & 7, b = xcd >> 1;
    const int chunk = ((bid >> 3) << 1) | (xcd & 1);
    const int n  = chunk * 16 + (threadIdx.x >> 4);
    const int cq = (threadIdx.x & 15) * 4;

    const f32x4 d4 = *reinterpret_cast<const f32x4*>(nn_dist + (size_t)n * 4);
    const i32x4 id = *reinterpret_cast<const i32x4*>(nn_idx + (size_t)n * 4);
    const float i0 = 1.0f / (d4.x + IWD_EPS), i1 = 1.0f / (d4.y + IWD_EPS);
    const float i2 = 1.0f / (d4.z + IWD_EPS), i3 = 1.0f / (d4.w + IWD_EPS);
    const float r = 1.0f / (i0 + i1 + i2 + i3);
    const float w0 = i0 * r, w1 = i1 * r, w2 = i2 * r, w3 = i3 * r;

    const float* xb = x + (size_t)b * N_in * C;
    const f32x4 a0 = *reinterpret_cast<const f32x4*>(xb + (size_t)id.x * C + cq);
    const f32x4 a1 = *reinterpret_cast<const f32x4*>(xb + (size_t)id.y * C + cq);
    const f32x4 a2 = *reinterpret_cast<const f32x4*>(xb + (size_t)id.z * C + cq);
    const f32x4 a3 = *reinterpret_cast<const f32x4*>(xb + (size_t)id.w * C + cq);
    const f32x4 o = a0 * w0 + a1 * w1 + a2 * w2 + a3 * w3;
    __builtin_nontemporal_store(
        o, reinterpret_cast<f32x4*>(out + ((size_t)b * N_out + n) * C + cq));
}

extern "C" void kernel_launch(void* const* d_in, const int* in_sizes, int n_in,
                              void* d_out, int out_size, void* d_ws, size_t ws_size,
                              hipStream_t stream) {
    const float* x       = (const float*)d_in[0];
    const int*   nn_idx  = (const int*)d_in[1];
    const float* nn_dist = (const float*)d_in[2];
    float*       out     = (float*)d_out;

    constexpr int B = 4, N_in = 49152, C = 64, N_out = 196608;
    constexpr size_t WREC_BYTES = (size_t)N_out * 32;       // 6.29 MB
    constexpr size_t XS_BYTES   = (size_t)B * N_in * C * 2; // 25.2 MB

    if (ws_size >= WREC_BYTES + XS_BYTES) {
        unsigned int*   wrec = (unsigned int*)d_ws;
        unsigned short* xs   = (unsigned short*)((char*)d_ws + WREC_BYTES);

        const int nvec8 = B * N_in * C / 8;        // 1,572,864
        const int nconvblocks = nvec8 / 256;       // 6144 (exact)
        const int nwblocks = N_out / 256;          // 768 (exact)
        iwd_pre_kernel<<<nconvblocks + nwblocks, 256, 0, stream>>>(
            x, nn_idx, nn_dist, xs, wrec, nconvblocks, nvec8);

        // 2 rows per 8-lane group; 64 rows per block per (b,h) job.
        const int grid = (N_out / 64) * B * 2;     // 24576
        IWD_ProjLayer_65876208386401_kernel<<<grid, 256, 0, stream>>>(xs, wrec, out);
    } else {
        const int grid = (N_out / 16) * B;         // 49152
        iwd_f32_fallback_kernel<<<grid, 256, 0, stream>>>(x, nn_idx, nn_dist, out);
    }
}